// Round 1
// baseline (116.796 us; speedup 1.0000x reference)
//
#include <hip/hip_runtime.h>
#include <math.h>

// CRF loss: B=256, L=256, T=50.
// R11: eliminate per-step cross-lane traffic from the serial scan chain.
//   R10's step was: pack -> 8 ds_bpermute -> lgkmcnt wait -> 8 MFMA
//   (A = alpha broadcast rows, B = E2 const). The bpermute round-trip
//   dominated the 128-step serial dependency chain (294912 bank-conflict
//   cycles, MfmaUtil 6%, VALUBusy 12% -> pure latency-bound).
//   R11 swaps operand roles: A = E2^T constant frags (IDENTICAL packed
//   values to R10's Bfr; A-frag row index is lane's n, K-slot is lane's q),
//   B = alpha bf16 K-pairs broadcast over the 16 columns. The MFMA C layout
//   (row = 4q+reg, replicated over n) then lands alpha_new[16I+4q+r] on the
//   very lane that packs the next B-frag slot (tag 16c+4q+r):
//     B0.i[r] = pair(va[r],   va[8+r])    (tags 4q+r,    4q+r+32)
//     B1.i[r] = pair(va[4+r], va[12+r])   (tags 16+4q+r, 48+4q+r)
//   -> recurrence is 100% lane-local: 8 packs + 8 MFMA + ~40 VALU, no LDS
//   on the chain. Emissions are exp2'd ONCE in preload into a padded
//   [l][64] LDS table; the 16 per-step eh values come from 4 conflict-free
//   broadcast ds_read_b128, prefetched one step ahead. Pads stay exactly 0
//   (zero table columns x zero A-frag rows) so no NaN enters the packs.
// Renorm (stale pivot, alpha = v*2^S), mask handling, fwd/bwd split,
// ws layout and the combine kernel are R10-verbatim.

#define TAGS 50
#define LEN 256
#define NB 256
#define HALF 128
#define INV_LN2 1.4426950408889634f
#define LN2 0.6931471805599453f

typedef __attribute__((ext_vector_type(8))) short bf16x8;
typedef __attribute__((ext_vector_type(4))) float f32x4;

#if __has_builtin(__builtin_amdgcn_exp2f)
#define EXP2F(x) __builtin_amdgcn_exp2f(x)
#else
#define EXP2F(x) exp2f(x)
#endif
#if __has_builtin(__builtin_amdgcn_logf)
#define LOG2F(x) __builtin_amdgcn_logf(x)
#else
#define LOG2F(x) log2f(x)
#endif
#if __has_builtin(__builtin_amdgcn_rcpf)
#define RCPF(x) __builtin_amdgcn_rcpf(x)
#else
#define RCPF(x) (1.0f / (x))
#endif

__device__ __forceinline__ float readlane_f(float v, int srclane) {
  return __builtin_bit_cast(float,
      __builtin_amdgcn_readlane(__builtin_bit_cast(int, v), srclane));
}

// Pack two fp32 into one VGPR as (bf16(hi) << 16) | bf16(lo), round-half-up.
__device__ __forceinline__ int bf16pair(float lo, float hi) {
  unsigned lb = (__builtin_bit_cast(unsigned, lo) + 0x8000u) >> 16;
  unsigned hb = (__builtin_bit_cast(unsigned, hi) + 0x8000u) & 0xFFFF0000u;
  return (int)(hb | lb);
}

union U8 { int i[4]; bf16x8 v; };

// ws layout (floats): u[NB][64] | w[NB][64] | Sf[NB] | Sb[NB]
#define WS_U(b)  ((b) * 64)
#define WS_W(b)  ((NB + (b)) * 64)
#define WS_SF(b) (2 * NB * 64 + (b))
#define WS_SB(b) (2 * NB * 64 + NB + (b))

__global__ __launch_bounds__(64) void crf_scan_kernel(
    const float* __restrict__ feats,   // (B, L, T)
    const float* __restrict__ trans,   // (T, T)
    const int*   __restrict__ mask,    // (B, L)
    float*       __restrict__ ws)
{
  const int bid    = blockIdx.x;
  const bool is_fwd = bid < NB;
  const int b      = is_fwd ? bid : bid - NB;
  const int lane   = threadIdx.x;
  const int q      = lane >> 4;
  const int n      = lane & 15;

  __shared__ __align__(16) float fraw[HALF * TAGS];  // log2-scaled emissions
  __shared__ __align__(16) float flexp[HALF * 64];   // exp2(emissions), padded cols 50..63 = 0
  __shared__ int ml[HALF];

  const int base_l = is_fwd ? 0 : HALF;
  const float* fb = feats + ((size_t)b * LEN + base_l) * TAGS;
  const int*   mb = mask + b * LEN + base_l;

  // ---- Preload phase 1 (proven float4 pattern): feats -> fraw (x 1/ln2) ----
  {
    const float4* fv = (const float4*)fb;
    for (int i = lane; i < (HALF * TAGS) / 4; i += 64) {
      float4 v4 = fv[i];
      v4.x *= INV_LN2; v4.y *= INV_LN2; v4.z *= INV_LN2; v4.w *= INV_LN2;
      *(float4*)&fraw[i * 4] = v4;
    }
    for (int i = lane; i < HALF; i += 64) ml[i] = mb[i];
  }
  __syncthreads();

  // ---- Preload phase 2: exp2 into padded [l][64] table (pads = 0) ----
  for (int l = 0; l < HALF; ++l) {
    float v = 0.0f;
    if (lane < TAGS) v = EXP2F(fraw[l * TAGS + lane]);
    flexp[l * 64 + lane] = v;
  }
  __syncthreads();

  // ---- Constant A-frags = E2^T (fwd) / E2 (bwd). Same packed values as
  //      R10's Bfr: row index = n (A layout), K-permutation by own q. ----
  U8 Afr[4][2];
#pragma unroll
  for (int t = 0; t < 4; ++t)
#pragma unroll
    for (int c = 0; c < 2; ++c)
#pragma unroll
      for (int r = 0; r < 4; ++r) {
        const int col = 16 * t + n;
        const int tag0 = 16 * c + 4 * q + r;
        const int tag1 = tag0 + 32;
        float e0 = 0.0f, e1 = 0.0f;
        if (col < TAGS) {
          if (tag0 < TAGS)
            e0 = EXP2F((is_fwd ? trans[tag0 * TAGS + col]
                               : trans[col * TAGS + tag0]) * INV_LN2);
          if (tag1 < TAGS)
            e1 = EXP2F((is_fwd ? trans[tag1 * TAGS + col]
                               : trans[col * TAGS + tag1]) * INV_LN2);
        }
        Afr[t][c].i[r] = bf16pair(e0, e1);
      }

  const f32x4 zero4 = {0.0f, 0.0f, 0.0f, 0.0f};

  // eh loads: row l, row-block I -> floats [l*64 + 16I + 4q .. +3], 16B aligned,
  // 4 distinct broadcast addresses per instruction -> conflict-free.
#define LDEH(l_, I_) (*(const f32x4*)&flexp[(l_) * 64 + 16 * (I_) + 4 * q])

  // State: va[4I+r] = alpha[16I+4q+r] * 2^-S, replicated over n.
  float va[16];
  float S;

  if (is_fwd) {
    // ---- Forward: u = v0 . M1..M127 (127 steps) ----
    const float r0 = RCPF(flexp[0]);
    {
      f32x4 i0 = LDEH(0, 0), i1 = LDEH(0, 1), i2 = LDEH(0, 2), i3 = LDEH(0, 3);
#pragma unroll
      for (int r = 0; r < 4; ++r) {
        va[r]      = i0[r] * r0;
        va[4 + r]  = i1[r] * r0;
        va[8 + r]  = i2[r] * r0;
        va[12 + r] = i3[r] * r0;
      }
    }
    S = fraw[0];

    f32x4 eh0 = LDEH(1, 0), eh1 = LDEH(1, 1), eh2 = LDEH(1, 2), eh3 = LDEH(1, 3);
    int m_nxt = ml[1];

#pragma unroll 2
    for (int l = 1; l < HALF; ++l) {
      const int m_cur = m_nxt;
      const int ln = (l + 1 < HALF) ? (l + 1) : (HALF - 1);

      const float cc = readlane_f(va[0], 0);
      const float rr = RCPF(cc);

      U8 B0, B1;
#pragma unroll
      for (int r = 0; r < 4; ++r) {
        B0.i[r] = bf16pair(va[r],     va[8 + r]);
        B1.i[r] = bf16pair(va[4 + r], va[12 + r]);
      }

      f32x4 d0 = __builtin_amdgcn_mfma_f32_16x16x32_bf16(Afr[0][1].v, B1.v, zero4, 0, 0, 0);
      f32x4 d1 = __builtin_amdgcn_mfma_f32_16x16x32_bf16(Afr[1][1].v, B1.v, zero4, 0, 0, 0);
      f32x4 d2 = __builtin_amdgcn_mfma_f32_16x16x32_bf16(Afr[2][1].v, B1.v, zero4, 0, 0, 0);
      f32x4 d3 = __builtin_amdgcn_mfma_f32_16x16x32_bf16(Afr[3][1].v, B1.v, zero4, 0, 0, 0);
      d0 = __builtin_amdgcn_mfma_f32_16x16x32_bf16(Afr[0][0].v, B0.v, d0, 0, 0, 0);
      d1 = __builtin_amdgcn_mfma_f32_16x16x32_bf16(Afr[1][0].v, B0.v, d1, 0, 0, 0);
      d2 = __builtin_amdgcn_mfma_f32_16x16x32_bf16(Afr[2][0].v, B0.v, d2, 0, 0, 0);
      d3 = __builtin_amdgcn_mfma_f32_16x16x32_bf16(Afr[3][0].v, B0.v, d3, 0, 0, 0);

      // prefetch next-step eh + mask (hidden under MFMA)
      f32x4 en0 = LDEH(ln, 0), en1 = LDEH(ln, 1), en2 = LDEH(ln, 2), en3 = LDEH(ln, 3);
      const int m_n2 = ml[ln];

#pragma unroll
      for (int r = 0; r < 4; ++r) {
        va[r]      = ((m_cur > 0) ? d0[r] * eh0[r] : va[r])      * rr;
        va[4 + r]  = ((m_cur > 0) ? d1[r] * eh1[r] : va[4 + r])  * rr;
        va[8 + r]  = ((m_cur > 0) ? d2[r] * eh2[r] : va[8 + r])  * rr;
        va[12 + r] = ((m_cur > 0) ? d3[r] * eh3[r] : va[12 + r]) * rr;
      }
      S += LOG2F(cc);
      eh0 = en0; eh1 = en1; eh2 = en2; eh3 = en3;
      m_nxt = m_n2;
    }

    if (n == 0) {
#pragma unroll
      for (int I = 0; I < 4; ++I)
#pragma unroll
        for (int r = 0; r < 4; ++r)
          ws[WS_U(b) + 16 * I + 4 * q + r] = va[4 * I + r];
    }
    if (lane == 0) ws[WS_SF(b)] = S;
  } else {
    // ---- Backward: w = M128..M255 . 1 (128 steps, l_local 127..0) ----
#pragma unroll
    for (int I = 0; I < 4; ++I)
#pragma unroll
      for (int r = 0; r < 4; ++r)
        va[4 * I + r] = (16 * I + 4 * q + r < TAGS) ? 1.0f : 0.0f;
    S = 0.0f;

    f32x4 eh0 = LDEH(HALF - 1, 0), eh1 = LDEH(HALF - 1, 1),
          eh2 = LDEH(HALF - 1, 2), eh3 = LDEH(HALF - 1, 3);
    int m_nxt = ml[HALF - 1];

#pragma unroll 2
    for (int l = HALF - 1; l >= 0; --l) {
      const int m_cur = m_nxt;
      const int ln = (l > 0) ? (l - 1) : 0;

      const float cc = readlane_f(va[0], 0);
      const float rr = RCPF(cc);

      // x = eh_l .* w (pads: both 0)
      float x[16];
#pragma unroll
      for (int r = 0; r < 4; ++r) {
        x[r]      = va[r]      * eh0[r];
        x[4 + r]  = va[4 + r]  * eh1[r];
        x[8 + r]  = va[8 + r]  * eh2[r];
        x[12 + r] = va[12 + r] * eh3[r];
      }

      U8 B0, B1;
#pragma unroll
      for (int r = 0; r < 4; ++r) {
        B0.i[r] = bf16pair(x[r],     x[8 + r]);
        B1.i[r] = bf16pair(x[4 + r], x[12 + r]);
      }

      f32x4 d0 = __builtin_amdgcn_mfma_f32_16x16x32_bf16(Afr[0][1].v, B1.v, zero4, 0, 0, 0);
      f32x4 d1 = __builtin_amdgcn_mfma_f32_16x16x32_bf16(Afr[1][1].v, B1.v, zero4, 0, 0, 0);
      f32x4 d2 = __builtin_amdgcn_mfma_f32_16x16x32_bf16(Afr[2][1].v, B1.v, zero4, 0, 0, 0);
      f32x4 d3 = __builtin_amdgcn_mfma_f32_16x16x32_bf16(Afr[3][1].v, B1.v, zero4, 0, 0, 0);
      d0 = __builtin_amdgcn_mfma_f32_16x16x32_bf16(Afr[0][0].v, B0.v, d0, 0, 0, 0);
      d1 = __builtin_amdgcn_mfma_f32_16x16x32_bf16(Afr[1][0].v, B0.v, d1, 0, 0, 0);
      d2 = __builtin_amdgcn_mfma_f32_16x16x32_bf16(Afr[2][0].v, B0.v, d2, 0, 0, 0);
      d3 = __builtin_amdgcn_mfma_f32_16x16x32_bf16(Afr[3][0].v, B0.v, d3, 0, 0, 0);

      f32x4 en0 = LDEH(ln, 0), en1 = LDEH(ln, 1), en2 = LDEH(ln, 2), en3 = LDEH(ln, 3);
      const int m_n2 = ml[ln];

#pragma unroll
      for (int r = 0; r < 4; ++r) {
        va[r]      = ((m_cur > 0) ? d0[r] : va[r])      * rr;
        va[4 + r]  = ((m_cur > 0) ? d1[r] : va[4 + r])  * rr;
        va[8 + r]  = ((m_cur > 0) ? d2[r] : va[8 + r])  * rr;
        va[12 + r] = ((m_cur > 0) ? d3[r] : va[12 + r]) * rr;
      }
      S += LOG2F(cc);
      eh0 = en0; eh1 = en1; eh2 = en2; eh3 = en3;
      m_nxt = m_n2;
    }

    if (n == 0) {
#pragma unroll
      for (int I = 0; I < 4; ++I)
#pragma unroll
        for (int r = 0; r < 4; ++r)
          ws[WS_W(b) + 16 * I + 4 * q + r] = va[4 * I + r];
    }
    if (lane == 0) ws[WS_SB(b)] = S;
  }
#undef LDEH
}

__global__ __launch_bounds__(64) void crf_combine_kernel(
    const float* __restrict__ feats,   // (B, L, T)
    const float* __restrict__ trans,   // (T, T)
    const int*   __restrict__ tags,    // (B, L)
    const int*   __restrict__ mask,    // (B, L)
    const float* __restrict__ ws,
    float*       __restrict__ out)     // (B,)
{
  const int b = blockIdx.x;
  const int lane = threadIdx.x;

  // normalizer = ln2 * (Sf + Sb + log2(sum_tag u*w))   (pads are 0)
  float s = ws[WS_U(b) + lane] * ws[WS_W(b) + lane];
#pragma unroll
  for (int off = 32; off; off >>= 1) s += __shfl_xor(s, off, 64);

  // gold score: lane handles positions lane, +64, +128, +192
  const float* fb = feats + (size_t)b * (LEN * TAGS);
  const int*   tb = tags + b * LEN;
  const int*   mb = mask + b * LEN;
  float gp = 0.0f;
#pragma unroll
  for (int k = 0; k < 4; ++k) {
    const int p = lane + 64 * k;
    const int tg = tb[p];
    if (mb[p] > 0) {
      float vv = fb[p * TAGS + tg];
      if (p >= 1) vv += trans[tb[p - 1] * TAGS + tg];
      gp += vv;
    }
  }
#pragma unroll
  for (int off = 32; off; off >>= 1) gp += __shfl_xor(gp, off, 64);

  if (lane == 0) {
    const float Sf = ws[WS_SF(b)];
    const float Sb = ws[WS_SB(b)];
    out[b] = LN2 * (Sf + Sb + LOG2F(s)) - gp;
  }
}

extern "C" void kernel_launch(void* const* d_in, const int* in_sizes, int n_in,
                              void* d_out, int out_size, void* d_ws, size_t ws_size,
                              hipStream_t stream) {
  const float* feats = (const float*)d_in[0];
  const float* trans = (const float*)d_in[1];
  const int*   tags  = (const int*)d_in[2];
  const int*   mask  = (const int*)d_in[3];
  float* out = (float*)d_out;
  float* ws  = (float*)d_ws;   // needs (2*256*64 + 512) * 4 = 133 KB

  crf_scan_kernel<<<2 * NB, 64, 0, stream>>>(feats, trans, mask, ws);
  crf_combine_kernel<<<NB, 64, 0, stream>>>(feats, trans, tags, mask, ws, out);
}